// Round 2
// baseline (186.709 us; speedup 1.0000x reference)
//
#include <hip/hip_runtime.h>

#define T_DIM 2048
#define F_DIM 16
#define B_DIM 1024
#define STEPS 300
#define TC 304  // padded leading dim for F

// ws layout (bytes):
//   F      @ 0         : 4*1024*304*4 = 4,980,736   float F[(j*1024+b)*304 + t]
//   cbuf   @ 4,980,736 : 16,384                      float c[j*1024 + b]
//   NZ     @ 4,997,120 : 163,840                     u64 NZ[(j*1024+b)*5 + w]
//   validw @ 5,160,960 : 160                         u64 validw[j*5 + w]
#define OFF_CBUF  (4u * B_DIM * TC * 4u)
#define OFF_NZ    (OFF_CBUF + 4u * B_DIM * 4u)
#define OFF_VALID (OFF_NZ + 4u * B_DIM * 5u * 8u)

// kA: compact-copy features 10..13 for t<300, build nonzero bitmaps, per-b constants.
__global__ void __launch_bounds__(320) kA(const float* __restrict__ x,
                                          const float* __restrict__ wptr,
                                          float* __restrict__ F,
                                          float* __restrict__ cbuf,
                                          unsigned long long* __restrict__ NZ,
                                          unsigned long long* __restrict__ validw) {
#pragma clang fp contract(off)
    int b = blockIdx.x;
    int t = threadIdx.x;
    if (b == 0 && t < 20) validw[t] = 0ull;  // ws is poisoned 0xAA each call

    if (t == 0) {  // per-batch constants from x_last row
        const float* xl = x + ((size_t)b * T_DIM + (T_DIM - 1)) * F_DIM;
        float w = *wptr;
        float d = 0.0f;
#pragma unroll
        for (int j0 = 0; j0 < 4; ++j0) {
            d = d + xl[j0];                      // sequential prefix sum == np.sum order
            float den = w + xl[5 + j0] * 25.0f;  // no FMA (contract off)
            float td  = (d * 150.0f) / den;      // IEEE div
            cbuf[j0 * B_DIM + b] = td * 10.0f;
        }
    }

    float v0 = 0.f, v1 = 0.f, v2 = 0.f, v3 = 0.f;
    bool act = t < STEPS;
    if (act) {
        const float* row = x + ((size_t)b * T_DIM + t) * F_DIM;
        float2 p0 = *(const float2*)(row + 10);  // feats 10,11 (8B-aligned)
        float2 p1 = *(const float2*)(row + 12);  // feats 12,13
        v0 = p0.x; v1 = p0.y; v2 = p1.x; v3 = p1.y;
        F[((size_t)(0 * B_DIM + b)) * TC + t] = v0;
        F[((size_t)(1 * B_DIM + b)) * TC + t] = v1;
        F[((size_t)(2 * B_DIM + b)) * TC + t] = v2;
        F[((size_t)(3 * B_DIM + b)) * TC + t] = v3;
    }
    unsigned long long m0 = __ballot(act && v0 != 0.f);
    unsigned long long m1 = __ballot(act && v1 != 0.f);
    unsigned long long m2 = __ballot(act && v2 != 0.f);
    unsigned long long m3 = __ballot(act && v3 != 0.f);
    int w = t >> 6;
    if ((t & 63) == 0) {
        NZ[((size_t)(0 * B_DIM + b)) * 5 + w] = m0;
        NZ[((size_t)(1 * B_DIM + b)) * 5 + w] = m1;
        NZ[((size_t)(2 * B_DIM + b)) * 5 + w] = m2;
        NZ[((size_t)(3 * B_DIM + b)) * 5 + w] = m3;
    }
}

// kB: thread per (w, j, b) builds one 64-bit word of valid[j], wave-OR, atomicOr.
__global__ void __launch_bounds__(256) kB(const float* __restrict__ cbuf,
                                          const unsigned long long* __restrict__ NZ,
                                          unsigned long long* __restrict__ validw) {
#pragma clang fp contract(off)
    int tid = blockIdx.x * 256 + threadIdx.x;  // 0..20479
    int b  = tid & 1023;
    int wj = tid >> 10;      // 0..19
    int j  = wj & 3;
    int w  = wj >> 2;        // 0..4
    float c = cbuf[j * B_DIM + b];
    const unsigned long long* nzp = NZ + (size_t)(j * B_DIM + b) * 5;
    unsigned long long nz0 = nzp[0], nz1 = nzp[1], nz2 = nzp[2], nz3 = nzp[3], nz4 = nzp[4];

    unsigned long long a = 0;
    int kmax = (w == 4) ? (STEPS - 256) : 64;
    for (int k = 0; k < kmax; ++k) {
        int i = w * 64 + k;
        float r = (float)i - c;    // same f32 rounding as reference
        int idx = (int)r;          // trunc toward zero == astype(int32)
        idx = idx < 0 ? 0 : (idx > STEPS - 1 ? STEPS - 1 : idx);  // c>=0 => idx<=i<=299
        unsigned long long word = idx < 64 ? nz0 : idx < 128 ? nz1 :
                                  idx < 192 ? nz2 : idx < 256 ? nz3 : nz4;
        a |= ((word >> (idx & 63)) & 1ull) << k;
    }
    // wave OR-reduce (lanes share (w,j), vary b)
    unsigned lo = (unsigned)a, hi = (unsigned)(a >> 32);
#pragma unroll
    for (int s = 32; s; s >>= 1) {
        lo |= __shfl_xor(lo, s, 64);
        hi |= __shfl_xor(hi, s, 64);
    }
    if ((threadIdx.x & 63) == 0) {
        unsigned long long red = ((unsigned long long)hi << 32) | lo;
        if (red) atomicOr(&validw[j * 5 + w], red);
    }
}

// kC: per (b,i) pick first valid j, gather from compact F, write out[b*300+i].
__global__ void __launch_bounds__(256) kC(const float* __restrict__ F,
                                          const float* __restrict__ cbuf,
                                          const unsigned long long* __restrict__ validw,
                                          float* __restrict__ out) {
#pragma clang fp contract(off)
    int g = blockIdx.x * 256 + threadIdx.x;
    if (g >= B_DIM * STEPS) return;
    int b = g / STEPS;
    int i = g - b * STEPS;
    int wi = i >> 6, bi = i & 63;
    unsigned m = 0;
#pragma unroll
    for (int j = 0; j < 4; ++j)
        m |= (unsigned)((validw[j * 5 + wi] >> bi) & 1ull) << j;
    float r = 0.0f;
    if (m) {
        int j = __ffs(m) - 1;  // argmax of bool row == first True
        float c = cbuf[j * B_DIM + b];
        float rr = (float)i - c;
        int idx = (int)rr;
        idx = idx < 0 ? 0 : (idx > STEPS - 1 ? STEPS - 1 : idx);
        r = F[(size_t)(j * B_DIM + b) * TC + idx];
    }
    out[g] = r;
}

extern "C" void kernel_launch(void* const* d_in, const int* in_sizes, int n_in,
                              void* d_out, int out_size, void* d_ws, size_t ws_size,
                              hipStream_t stream) {
    const float* x    = (const float*)d_in[3];
    const float* wptr = (const float*)d_in[4];
    float* out = (float*)d_out;  // (1024, 300) row-major

    float*              Fbuf   = (float*)d_ws;
    float*              cbuf   = (float*)((char*)d_ws + OFF_CBUF);
    unsigned long long* NZ     = (unsigned long long*)((char*)d_ws + OFF_NZ);
    unsigned long long* validw = (unsigned long long*)((char*)d_ws + OFF_VALID);

    hipLaunchKernelGGL(kA, dim3(B_DIM), dim3(320), 0, stream, x, wptr, Fbuf, cbuf, NZ, validw);
    hipLaunchKernelGGL(kB, dim3(80), dim3(256), 0, stream, cbuf, NZ, validw);
    hipLaunchKernelGGL(kC, dim3((B_DIM * STEPS + 255) / 256), dim3(256), 0, stream,
                       Fbuf, cbuf, validw, out);
}